// Round 7
// baseline (146.087 us; speedup 1.0000x reference)
//
#include <hip/hip_runtime.h>
#include <hip/hip_cooperative_groups.h>

namespace cg = cooperative_groups;

#define BATCH 8192
#define NF 1024
#define NS 50000
#define MOM 0.2f
#define MAXOCC 64     // max tracked occurrences of one label (random max ~4)
#define GBLK 2048     // persistent blocks in fused_bank (8 per CU)
#define PRE_BLKS 256  // cooperative prelude grid

// ---------------------------------------------------------------------------
// Prelude (single cooperative dispatch): sentinel-init first/lastm, grid.sync,
// then 2 atomicMin per batch slot.
// table = [first: NS ints][lastm: NS ints]; lastm[y] = BATCH-1-max(i).
__global__ __launch_bounds__(256)
void prelude(const int* __restrict__ labels, int* __restrict__ table) {
    const int idx = blockIdx.x * 256 + threadIdx.x;
    for (int t = idx; t < 2 * NS; t += PRE_BLKS * 256) table[t] = 0x7f7f7f7f;
    cg::this_grid().sync();
    if (idx < BATCH) {
        const int y = labels[idx];
        atomicMin(&table[y], idx);
        atomicMin(&table[NS + y], BATCH - 1 - idx);
    }
}

// momentum blend + block-reduced L2 normalize (256 threads = 4 waves)
__device__ __forceinline__ void blend_normalize(float4& v, const float4 x,
                                                float* s_part, int tid) {
    const float m = MOM, om = 1.0f - MOM;
    v.x = m * v.x + om * x.x;
    v.y = m * v.y + om * x.y;
    v.z = m * v.z + om * x.z;
    v.w = m * v.w + om * x.w;
    float s = v.x * v.x + v.y * v.y + v.z * v.z + v.w * v.w;
    for (int off = 32; off; off >>= 1) s += __shfl_xor(s, off, 64);
    if ((tid & 63) == 0) s_part[tid >> 6] = s;
    __syncthreads();
    const float tot = s_part[0] + s_part[1] + s_part[2] + s_part[3];
    __syncthreads();   // protect s_part before any later reuse
    const float inv = 1.0f / sqrtf(tot);
    v.x *= inv; v.y *= inv; v.z *= inv; v.w *= inv;
}

// ---------------------------------------------------------------------------
// 2048 persistent blocks; each streams rows bid, bid+GBLK, ... with a depth-2
// pipeline: row n+2's float4 + metadata are in flight while row n is processed.
// Untouched rows: register copy. Single occurrence: one blend+normalize.
// Multi-occurrence (~640 labels): in-block scan of the 32KB label array.
__global__ __launch_bounds__(256)
void fused_bank(const float* __restrict__ f_out,
                const float* __restrict__ features,
                const int* __restrict__ labels,
                const int* __restrict__ first,
                const int* __restrict__ lastm,
                float* __restrict__ out) {
    const int tid = threadIdx.x;
    const int bid = blockIdx.x;
    const float4* feat4 = reinterpret_cast<const float4*>(features);
    const float4* fout4 = reinterpret_cast<const float4*>(f_out);
    float4* out4 = reinterpret_cast<float4*>(out);

    __shared__ float s_part[4];
    __shared__ int s_cnt;
    __shared__ int s_idx[MAXOCC];

    int y0 = bid;
    int y1 = y0 + GBLK;
    float4 v0{}, v1{};
    int h0 = 0, l0 = 0, h1 = 0, l1 = 0;
    if (y0 < NS) {
        v0 = feat4[(size_t)y0 * (NF / 4) + tid];
        h0 = first[y0];  l0 = lastm[y0];
    }
    if (y1 < NS) {
        v1 = feat4[(size_t)y1 * (NF / 4) + tid];
        h1 = first[y1];  l1 = lastm[y1];
    }

    while (y0 < NS) {
        // prefetch row y0 + 2*GBLK
        const int y2 = y1 + GBLK;
        float4 v2{};
        int h2 = 0, l2 = 0;
        if (y2 < NS) {
            v2 = feat4[(size_t)y2 * (NF / 4) + tid];
            h2 = first[y2];  l2 = lastm[y2];
        }

        // process row y0 (all branches block-uniform)
        if (h0 < BATCH) {
            const int last = BATCH - 1 - l0;
            if (h0 == last) {
                blend_normalize(v0, fout4[(size_t)h0 * (NF / 4) + tid], s_part, tid);
            } else {
                if (tid == 0) s_cnt = 0;
                __syncthreads();
                const int y = y0;
                for (int j = tid; j < BATCH; j += 256) {
                    if (labels[j] == y) {
                        const int p = atomicAdd(&s_cnt, 1);
                        if (p < MAXOCC) s_idx[p] = j;
                    }
                }
                __syncthreads();
                const int n = min(s_cnt, MAXOCC);
                if (tid == 0) {          // insertion-sort tiny list ascending
                    for (int a = 1; a < n; ++a) {
                        const int key = s_idx[a];
                        int b = a - 1;
                        while (b >= 0 && s_idx[b] > key) { s_idx[b + 1] = s_idx[b]; --b; }
                        s_idx[b + 1] = key;
                    }
                }
                __syncthreads();
                for (int t = 0; t < n; ++t)
                    blend_normalize(v0, fout4[(size_t)s_idx[t] * (NF / 4) + tid],
                                    s_part, tid);
            }
        }
        out4[(size_t)y0 * (NF / 4) + tid] = v0;

        y0 = y1; v0 = v1; h0 = h1; l0 = l1;
        y1 = y2; v1 = v2; h1 = h2; l1 = l2;
    }
}

extern "C" void kernel_launch(void* const* d_in, const int* in_sizes, int n_in,
                              void* d_out, int out_size, void* d_ws, size_t ws_size,
                              hipStream_t stream) {
    const float* f_out    = (const float*)d_in[0];
    const float* features = (const float*)d_in[1];
    const int*   labels   = (const int*)d_in[2];
    float* out = (float*)d_out;

    int* table = (int*)d_ws;            // [first: NS][lastm: NS]
    int* first = table;
    int* lastm = table + NS;

    void* pre_args[] = { (void*)&labels, (void*)&table };
    hipLaunchCooperativeKernel(reinterpret_cast<void*>(prelude),
                               dim3(PRE_BLKS), dim3(256), pre_args, 0, stream);

    fused_bank<<<GBLK, 256, 0, stream>>>(f_out, features, labels, first, lastm, out);
}

// Round 9
// 81.573 us; speedup vs baseline: 1.7909x; 1.7909x over previous
//
#include <hip/hip_runtime.h>

#define BATCH 8192
#define NF 1024
#define NS 50000
#define MOM 0.2f
#define MAXOCC 64
#define SENT 0xAAAAAAAAu   // harness poison == our sentinel (>= BATCH as unsigned)

typedef float floatx4 __attribute__((ext_vector_type(4)));  // NT-builtin-compatible

// ---------------------------------------------------------------------------
// k1: 2 unsigned atomicMin per batch slot. NO table init needed:
//  - poison 0xAAAAAAAA is a valid ">= BATCH" sentinel for unsigned min
//  - fused_bank restores every touched entry to SENT afterwards
//  - fused_bank is correct for arbitrary table garbage anyway (see guards)
__global__ void build_firstlast(const int* __restrict__ labels,
                                unsigned* __restrict__ first,
                                unsigned* __restrict__ lastm) {
    const int i = blockIdx.x * blockDim.x + threadIdx.x;
    if (i >= BATCH) return;
    const int y = labels[i];
    atomicMin(&first[y], (unsigned)i);
    atomicMin(&lastm[y], (unsigned)(BATCH - 1 - i));
}

// momentum blend + block-reduced L2 normalize (256 threads = 4 waves)
__device__ __forceinline__ void blend_normalize(floatx4& v, const float4 x,
                                                float* s_part, int tid) {
    const float m = MOM, om = 1.0f - MOM;
    v.x = m * v.x + om * x.x;
    v.y = m * v.y + om * x.y;
    v.z = m * v.z + om * x.z;
    v.w = m * v.w + om * x.w;
    float s = v.x * v.x + v.y * v.y + v.z * v.z + v.w * v.w;
    for (int off = 32; off; off >>= 1) s += __shfl_xor(s, off, 64);
    if ((tid & 63) == 0) s_part[tid >> 6] = s;
    __syncthreads();
    const float tot = s_part[0] + s_part[1] + s_part[2] + s_part[3];
    __syncthreads();   // protect s_part before any later reuse
    const float inv = 1.0f / sqrtf(tot);
    v.x *= inv; v.y *= inv; v.z *= inv; v.w *= inv;
}

// ---------------------------------------------------------------------------
// One block per bank row y (block-per-row was fastest: rounds 6 vs 3/7).
// Untouched rows: NT streaming copy. Verified single occurrence: one
// blend+normalize. Anything else (true duplicates, or garbage table):
// self-computing path — block scans the 32KB label array, sorts occurrences
// in LDS, applies in batch order. Correct for ANY initial table contents.
// Touched blocks restore their table entries to SENT (self-cleaning for the
// next graph replay; untouched entries are never modified).
__global__ __launch_bounds__(256)
void fused_bank(const float* __restrict__ f_out,
                const float* __restrict__ features,
                const int* __restrict__ labels,
                unsigned* __restrict__ first,
                unsigned* __restrict__ lastm,
                float* __restrict__ out) {
    const int y = blockIdx.x;
    const int tid = threadIdx.x;
    const floatx4* feat4 = reinterpret_cast<const floatx4*>(features);
    const float4* fout4 = reinterpret_cast<const float4*>(f_out);

    floatx4 v = __builtin_nontemporal_load(&feat4[(size_t)y * (NF / 4) + tid]);

    const unsigned h = first[y];       // block-uniform
    if (h < BATCH) {
        __shared__ float s_part[4];
        const unsigned lm = lastm[y];
        const unsigned last = BATCH - 1u - lm;   // huge if lm garbage >= BATCH
        // single-occurrence fast path: for labels truly present, atomicMin
        // guarantees h <= trueFirst and last >= trueLast, so h==last can only
        // happen at a genuine single occurrence; labels[h]==y rejects
        // absent-label garbage.
        if (h == last && labels[h] == (int)y) {
            blend_normalize(v, fout4[(size_t)h * (NF / 4) + tid], s_part, tid);
        } else {
            // self-computing path: collect all occurrences of y in batch order
            __shared__ int s_cnt;
            __shared__ int s_idx[MAXOCC];
            if (tid == 0) s_cnt = 0;
            __syncthreads();
            for (int j = tid; j < BATCH; j += 256) {
                if (labels[j] == y) {
                    const int p = atomicAdd(&s_cnt, 1);
                    if (p < MAXOCC) s_idx[p] = j;
                }
            }
            __syncthreads();
            const int n = min(s_cnt, MAXOCC);
            if (tid == 0) {            // insertion-sort tiny list ascending
                for (int a = 1; a < n; ++a) {
                    const int key = s_idx[a];
                    int b = a - 1;
                    while (b >= 0 && s_idx[b] > key) { s_idx[b + 1] = s_idx[b]; --b; }
                    s_idx[b + 1] = key;
                }
            }
            __syncthreads();
            for (int t = 0; t < n; ++t)
                blend_normalize(v, fout4[(size_t)s_idx[t] * (NF / 4) + tid],
                                s_part, tid);
        }
        if (tid == 0) {                // restore sentinel for next replay
            first[y] = SENT;
            lastm[y] = SENT;
        }
    }
    __builtin_nontemporal_store(v,
        &reinterpret_cast<floatx4*>(out)[(size_t)y * (NF / 4) + tid]);
}

extern "C" void kernel_launch(void* const* d_in, const int* in_sizes, int n_in,
                              void* d_out, int out_size, void* d_ws, size_t ws_size,
                              hipStream_t stream) {
    const float* f_out    = (const float*)d_in[0];
    const float* features = (const float*)d_in[1];
    const int*   labels   = (const int*)d_in[2];
    float* out = (float*)d_out;

    unsigned* first = (unsigned*)d_ws;   // NS unsigned
    unsigned* lastm = first + NS;        // NS unsigned

    build_firstlast<<<(BATCH + 255) / 256, 256, 0, stream>>>(labels, first, lastm);
    fused_bank<<<NS, 256, 0, stream>>>(f_out, features, labels, first, lastm, out);
}